// Round 1
// baseline (1267.293 us; speedup 1.0000x reference)
//
#include <hip/hip_runtime.h>
#include <math.h>

// ---------------------------------------------------------------------------
// CNNModel: 3 sparse grouped convs (fan-in 3/16/32) + dense 131072->50 ->10 + softmax
// B=64, H=W=32. All f32. Connectivity computed analytically (roll/kron structure).
// ---------------------------------------------------------------------------

#define BATCH 64

// ---------------- Layer 0: dense conv 3 -> 64, 3x3 SAME, ReLU --------------
__global__ void l0_kernel(const float* __restrict__ in, const float* __restrict__ w,
                          const float* __restrict__ bias, float* __restrict__ x0) {
    int tid = blockIdx.x * blockDim.x + threadIdx.x;  // B*32*32*64 = 4194304
    int n  = tid & 63;
    int wx = (tid >> 6) & 31;
    int hy = (tid >> 11) & 31;
    int b  = tid >> 16;
    float acc = bias[n];
    #pragma unroll
    for (int ky = 0; ky < 3; ++ky) {
        int y = hy + ky - 1;
        if ((unsigned)y >= 32u) continue;
        #pragma unroll
        for (int kx = 0; kx < 3; ++kx) {
            int x = wx + kx - 1;
            if ((unsigned)x >= 32u) continue;
            const float* px = in + ((b * 32 + y) * 32 + x) * 3;
            const float* pw = w + ((ky * 3 + kx) * 3) * 64 + n;
            acc += px[0] * pw[0] + px[1] * pw[64] + px[2] * pw[128];
        }
    }
    x0[tid] = fmaxf(acc, 0.f);
}

// ---------------- Layer 1: fan-in 16, 64 -> 128 nodes ----------------------
// node n: i0 = n&15; channels = 16*ci + S(i0)[m], f = 4*ci + m
// S(i0) = ascending sort of {(i0-k) mod 16, k=0..3}
__global__ void l1_kernel(const float* __restrict__ x0, const float* __restrict__ w,
                          const float* __restrict__ bias, float* __restrict__ x1) {
    int tid = blockIdx.x * blockDim.x + threadIdx.x;  // B*32*32*128 = 8388608
    int n  = tid & 127;
    int wx = (tid >> 7) & 31;
    int hy = (tid >> 12) & 31;
    int b  = tid >> 17;
    int i0 = n & 15;
    int S[4];
    #pragma unroll
    for (int m = 0; m < 4; ++m)
        S[m] = (i0 >= 3) ? (i0 - 3 + m) : ((m <= i0) ? m : (12 + m));
    float acc = bias[n];
    for (int ky = 0; ky < 3; ++ky) {
        int y = hy + ky - 1;
        if ((unsigned)y >= 32u) continue;
        for (int kx = 0; kx < 3; ++kx) {
            int x = wx + kx - 1;
            if ((unsigned)x >= 32u) continue;
            const float* px = x0 + ((b * 32 + y) * 32 + x) * 64;
            const float* pw = w + ((ky * 3 + kx) * 16) * 128 + n;
            #pragma unroll
            for (int ci = 0; ci < 4; ++ci) {
                #pragma unroll
                for (int m = 0; m < 4; ++m) {
                    acc += px[16 * ci + S[m]] * pw[(4 * ci + m) * 128];
                }
            }
        }
    }
    x1[tid] = fmaxf(acc, 0.f);
}

// ---------------- Layer 2: fan-in 32, 128 -> 128 nodes ---------------------
// node n: channels = 16*ci + (n&3) + 4*m, ci in 0..7, f = 4*ci + m
__global__ void l2_kernel(const float* __restrict__ x1, const float* __restrict__ w,
                          const float* __restrict__ bias, float* __restrict__ x2) {
    int tid = blockIdx.x * blockDim.x + threadIdx.x;  // 8388608
    int n  = tid & 127;
    int wx = (tid >> 7) & 31;
    int hy = (tid >> 12) & 31;
    int b  = tid >> 17;
    int g  = n & 3;
    float acc = bias[n];
    for (int ky = 0; ky < 3; ++ky) {
        int y = hy + ky - 1;
        if ((unsigned)y >= 32u) continue;
        for (int kx = 0; kx < 3; ++kx) {
            int x = wx + kx - 1;
            if ((unsigned)x >= 32u) continue;
            const float* px = x1 + ((b * 32 + y) * 32 + x) * 128;
            const float* pw = w + ((ky * 3 + kx) * 32) * 128 + n;
            #pragma unroll
            for (int ci = 0; ci < 8; ++ci) {
                #pragma unroll
                for (int m = 0; m < 4; ++m) {
                    acc += px[16 * ci + g + 4 * m] * pw[(4 * ci + m) * 128];
                }
            }
        }
    }
    x2[tid] = fmaxf(acc, 0.f);
}

// ---------------- Dense 1: [64,131072] x [131072,50] partial GEMM ----------
#define D1_NB 256
#define D1_KPB 512
#define D1_SUB 128
__global__ __launch_bounds__(320) void d1_kernel(const float* __restrict__ x2,
                                                 const float* __restrict__ dw1,
                                                 float* __restrict__ partial) {
    __shared__ float XT[D1_SUB][65];   // [k][b], padded
    __shared__ float WS[D1_SUB][52];   // [k][j]
    int t = threadIdx.x;
    int b = t & 63;
    int jg = t >> 6;  // 0..4
    float acc[10];
    #pragma unroll
    for (int jj = 0; jj < 10; ++jj) acc[jj] = 0.f;

    for (int r = 0; r < D1_KPB / D1_SUB; ++r) {
        int k0 = blockIdx.x * D1_KPB + r * D1_SUB;
        __syncthreads();
        for (int u = t; u < 64 * D1_SUB; u += 320) {
            int bb = u >> 7;
            int i  = u & (D1_SUB - 1);
            XT[i][bb] = x2[bb * 131072 + k0 + i];
        }
        for (int u = t; u < D1_SUB * 50; u += 320) {
            int i = u / 50;
            int j = u - i * 50;
            WS[i][j] = dw1[(k0 + i) * 50 + j];
        }
        __syncthreads();
        for (int k = 0; k < D1_SUB; ++k) {
            float xv = XT[k][b];
            #pragma unroll
            for (int jj = 0; jj < 10; ++jj)
                acc[jj] += xv * WS[k][jg * 10 + jj];
        }
    }
    float* po = partial + blockIdx.x * 3200 + b * 50 + jg * 10;
    #pragma unroll
    for (int jj = 0; jj < 10; ++jj) po[jj] = acc[jj];
}

// ---------------- Dense 1 reduce: sum 256 partials, deterministic ----------
__global__ void d1_reduce(const float* __restrict__ partial, float* __restrict__ h) {
    int t = blockIdx.x * blockDim.x + threadIdx.x;
    if (t >= 3200) return;
    float s0 = 0.f, s1 = 0.f, s2 = 0.f, s3 = 0.f;
    for (int cb = 0; cb < D1_NB; cb += 4) {
        s0 += partial[(cb + 0) * 3200 + t];
        s1 += partial[(cb + 1) * 3200 + t];
        s2 += partial[(cb + 2) * 3200 + t];
        s3 += partial[(cb + 3) * 3200 + t];
    }
    h[t] = (s0 + s1) + (s2 + s3);
}

// ---------------- Dense 2 + softmax ---------------------------------------
__global__ void d2_kernel(const float* __restrict__ h, const float* __restrict__ db1,
                          const float* __restrict__ dw2, const float* __restrict__ db2,
                          float* __restrict__ out) {
    int b = threadIdx.x;  // 0..63
    float a[10];
    #pragma unroll
    for (int j = 0; j < 10; ++j) a[j] = db2[j];
    for (int i = 0; i < 50; ++i) {
        float v = fmaxf(h[b * 50 + i] + db1[i], 0.f);
        #pragma unroll
        for (int j = 0; j < 10; ++j) a[j] += v * dw2[i * 10 + j];
    }
    float mx = a[0];
    #pragma unroll
    for (int j = 1; j < 10; ++j) mx = fmaxf(mx, a[j]);
    float s = 0.f;
    #pragma unroll
    for (int j = 0; j < 10; ++j) { a[j] = expf(a[j] - mx); s += a[j]; }
    float inv = 1.f / s;
    #pragma unroll
    for (int j = 0; j < 10; ++j) out[b * 10 + j] = a[j] * inv;
}

// ---------------------------------------------------------------------------
extern "C" void kernel_launch(void* const* d_in, const int* in_sizes, int n_in,
                              void* d_out, int out_size, void* d_ws, size_t ws_size,
                              hipStream_t stream) {
    const float* inputs = (const float*)d_in[0];
    const float* cw0 = (const float*)d_in[1];
    const float* cb0 = (const float*)d_in[2];
    const float* cw1 = (const float*)d_in[3];
    const float* cb1 = (const float*)d_in[4];
    const float* cw2 = (const float*)d_in[5];
    const float* cb2 = (const float*)d_in[6];
    const float* dw1 = (const float*)d_in[7];
    const float* db1 = (const float*)d_in[8];
    const float* dw2 = (const float*)d_in[9];
    const float* db2 = (const float*)d_in[10];
    float* out = (float*)d_out;

    float* ws = (float*)d_ws;
    // Overlapped layout (floats):
    //   x1       @ 0         (8388608)   live L1..L2
    //   x0       @ 8388608   (4194304)   live L0..L1
    //   x2       @ 8388608   (8388608)   live L2..D1 (overwrites dead x0)
    //   partial  @ 0         (819200)    live D1..reduce (overwrites dead x1)
    //   h        @ 819200    (3200)
    float* x1      = ws;
    float* x0      = ws + 8388608;
    float* x2      = ws + 8388608;
    float* partial = ws;
    float* h       = ws + 819200;

    l0_kernel<<<4194304 / 256, 256, 0, stream>>>(inputs, cw0, cb0, x0);
    l1_kernel<<<8388608 / 256, 256, 0, stream>>>(x0, cw1, cb1, x1);
    l2_kernel<<<8388608 / 256, 256, 0, stream>>>(x1, cw2, cb2, x2);
    d1_kernel<<<D1_NB, 320, 0, stream>>>(x2, dw1, partial);
    d1_reduce<<<13, 256, 0, stream>>>(partial, h);
    d2_kernel<<<1, 64, 0, stream>>>(h, db1, dw2, db2, out);
}

// Round 2
// 514.610 us; speedup vs baseline: 2.4626x; 2.4626x over previous
//
#include <hip/hip_runtime.h>
#include <math.h>

// CNNModel: 3 sparse grouped convs + dense 131072->50 ->10 + softmax. B=64, 32x32.
// Strategy: wave-uniform channel blocks -> weights via s_load (SGPR broadcast);
// one float4 activation load feeds 32 FMAs; borders via exec-mask.

struct __attribute__((packed, aligned(4))) f4u { float x, y, z, w; };

// ---------------- Layer 0: dense conv 3 -> 64 --------------------------------
__global__ __launch_bounds__(256) void l0_kernel(const float* __restrict__ in,
    const float* __restrict__ w, const float* __restrict__ bias, float* __restrict__ x0) {
    int bi = blockIdx.x;
    int n0 = (bi & 3) * 16;       // channel block
    int rb = (bi >> 2) & 3;       // row block of 8
    int b  = bi >> 4;
    int t = threadIdx.x, lane = t & 63, wv = t >> 6;
    int x = lane & 31;
    int row = rb * 8 + wv * 2 + (lane >> 5);

    float acc[16];
#pragma unroll
    for (int q = 0; q < 4; ++q)
#pragma unroll
        for (int g = 0; g < 4; ++g) acc[4 * q + g] = bias[n0 + 4 * q + g];

    for (int ky = 0; ky < 3; ++ky) {
        int yy = row + ky - 1;
        for (int kx = 0; kx < 3; ++kx) {
            int xx = x + kx - 1;
            if ((unsigned)yy < 32u && (unsigned)xx < 32u) {
                const float* pb = in + ((b * 32 + yy) * 32 + xx) * 3;
                float p0 = pb[0], p1 = pb[1], p2 = pb[2];
                const float* wb = w + (ky * 3 + kx) * 3 * 64 + n0;
#pragma unroll
                for (int c = 0; c < 3; ++c) {
                    float pc = (c == 0) ? p0 : ((c == 1) ? p1 : p2);
#pragma unroll
                    for (int q = 0; q < 4; ++q) {
                        float4 wq = *(const float4*)(wb + c * 64 + 4 * q);
                        acc[4*q+0] += pc * wq.x;
                        acc[4*q+1] += pc * wq.y;
                        acc[4*q+2] += pc * wq.z;
                        acc[4*q+3] += pc * wq.w;
                    }
                }
            }
        }
    }
    float* ob = x0 + ((b * 32 + row) * 32 + x) * 64 + n0;
#pragma unroll
    for (int q = 0; q < 4; ++q) {
        float4 o;
        o.x = fmaxf(acc[4*q+0], 0.f); o.y = fmaxf(acc[4*q+1], 0.f);
        o.z = fmaxf(acc[4*q+2], 0.f); o.w = fmaxf(acc[4*q+3], 0.f);
        *(float4*)(ob + 4 * q) = o;
    }
}

// ---------------- Layer 1: fan-in 16, 64 -> 128 ------------------------------
// Thread owns channels {c0+16q+g}; px float4 at c-base 16ci+(c0-3+m) pairs
// element g with channel c0+16q+g. Wrap block c0==0 uses lo/hi compile-time select.
__global__ __launch_bounds__(256) void l1_kernel(const float* __restrict__ x0,
    const float* __restrict__ w, const float* __restrict__ bias, float* __restrict__ x1) {
    int bi = blockIdx.x;
    int c0 = (bi & 3) * 4;        // 0,4,8,12
    int rb = (bi >> 2) & 3;
    int b  = bi >> 4;
    int t = threadIdx.x, lane = t & 63, wv = t >> 6;
    int x = lane & 31;
    int row = rb * 8 + wv * 2 + (lane >> 5);

    float acc[32];
#pragma unroll
    for (int q = 0; q < 8; ++q)
#pragma unroll
        for (int g = 0; g < 4; ++g) acc[4 * q + g] = bias[c0 + 16 * q + g];

    for (int ky = 0; ky < 3; ++ky) {
        int yy = row + ky - 1;
        for (int kx = 0; kx < 3; ++kx) {
            int xx = x + kx - 1;
            if ((unsigned)yy < 32u && (unsigned)xx < 32u) {
                const float* pb = x0 + ((b * 32 + yy) * 32 + xx) * 64;
                const float* wb = w + (ky * 3 + kx) * 16 * 128 + c0;
                if (c0) {
                    for (int ci = 0; ci < 4; ++ci) {
#pragma unroll
                        for (int m = 0; m < 4; ++m) {
                            f4u px = *(const f4u*)(pb + 16 * ci + (c0 - 3 + m));
                            const float* wf = wb + (4 * ci + m) * 128;
#pragma unroll
                            for (int q = 0; q < 8; ++q) {
                                float4 wq = *(const float4*)(wf + 16 * q);
                                acc[4*q+0] += px.x * wq.x;
                                acc[4*q+1] += px.y * wq.y;
                                acc[4*q+2] += px.z * wq.z;
                                acc[4*q+3] += px.w * wq.w;
                            }
                        }
                    }
                } else {
                    for (int ci = 0; ci < 4; ++ci) {
                        float4 lo = *(const float4*)(pb + 16 * ci);
                        float4 hi = *(const float4*)(pb + 16 * ci + 12);
#pragma unroll
                        for (int m = 0; m < 4; ++m) {
                            float lom = (m == 0) ? lo.x : (m == 1) ? lo.y : (m == 2) ? lo.z : lo.w;
                            float him = (m == 0) ? hi.x : (m == 1) ? hi.y : (m == 2) ? hi.z : hi.w;
                            float pv[4];
#pragma unroll
                            for (int g = 0; g < 4; ++g) pv[g] = (m <= g) ? lom : him;
                            const float* wf = wb + (4 * ci + m) * 128;
#pragma unroll
                            for (int q = 0; q < 8; ++q) {
                                float4 wq = *(const float4*)(wf + 16 * q);
                                acc[4*q+0] += pv[0] * wq.x;
                                acc[4*q+1] += pv[1] * wq.y;
                                acc[4*q+2] += pv[2] * wq.z;
                                acc[4*q+3] += pv[3] * wq.w;
                            }
                        }
                    }
                }
            }
        }
    }
    float* ob = x1 + ((b * 32 + row) * 32 + x) * 128 + c0;
#pragma unroll
    for (int q = 0; q < 8; ++q) {
        float4 o;
        o.x = fmaxf(acc[4*q+0], 0.f); o.y = fmaxf(acc[4*q+1], 0.f);
        o.z = fmaxf(acc[4*q+2], 0.f); o.w = fmaxf(acc[4*q+3], 0.f);
        *(float4*)(ob + 16 * q) = o;
    }
}

// ---------------- Layer 2: fan-in 32, 128 -> 128 -----------------------------
// c = 16ci + g + 4m independent of channel quad: one px float4 feeds 8 quads.
__global__ __launch_bounds__(256) void l2_kernel(const float* __restrict__ x1,
    const float* __restrict__ w, const float* __restrict__ bias, float* __restrict__ x2) {
    int bi = blockIdx.x;
    int n0 = (bi & 3) * 32;       // channel block
    int rb = (bi >> 2) & 3;
    int b  = bi >> 4;
    int t = threadIdx.x, lane = t & 63, wv = t >> 6;
    int x = lane & 31;
    int row = rb * 8 + wv * 2 + (lane >> 5);

    float acc[32];
#pragma unroll
    for (int q = 0; q < 8; ++q)
#pragma unroll
        for (int g = 0; g < 4; ++g) acc[4 * q + g] = bias[n0 + 4 * q + g];

    for (int ky = 0; ky < 3; ++ky) {
        int yy = row + ky - 1;
        for (int kx = 0; kx < 3; ++kx) {
            int xx = x + kx - 1;
            if ((unsigned)yy < 32u && (unsigned)xx < 32u) {
                const float* pb = x1 + ((b * 32 + yy) * 32 + xx) * 128;
                const float* wb = w + (ky * 3 + kx) * 32 * 128 + n0;
                for (int ci = 0; ci < 8; ++ci) {
#pragma unroll
                    for (int m = 0; m < 4; ++m) {
                        float4 px = *(const float4*)(pb + 16 * ci + 4 * m);
                        const float* wf = wb + (4 * ci + m) * 128;
#pragma unroll
                        for (int q = 0; q < 8; ++q) {
                            float4 wq = *(const float4*)(wf + 4 * q);
                            acc[4*q+0] += px.x * wq.x;
                            acc[4*q+1] += px.y * wq.y;
                            acc[4*q+2] += px.z * wq.z;
                            acc[4*q+3] += px.w * wq.w;
                        }
                    }
                }
            }
        }
    }
    float* ob = x2 + ((b * 32 + row) * 32 + x) * 128 + n0;
#pragma unroll
    for (int q = 0; q < 8; ++q) {
        float4 o;
        o.x = fmaxf(acc[4*q+0], 0.f); o.y = fmaxf(acc[4*q+1], 0.f);
        o.z = fmaxf(acc[4*q+2], 0.f); o.w = fmaxf(acc[4*q+3], 0.f);
        *(float4*)(ob + 4 * q) = o;
    }
}

// ---------------- Dense 1: [64,131072] x [131072,50] -------------------------
#define D1_NB 512
#define D1_KPB 256
#define D1_SUB 128
__global__ __launch_bounds__(320) void d1_kernel(const float* __restrict__ x2,
                                                 const float* __restrict__ dw1,
                                                 float* __restrict__ partial) {
    __shared__ float XT[D1_SUB][65];   // [k][b]
    int t = threadIdx.x;
    int b = t & 63;
    int jg = __builtin_amdgcn_readfirstlane(t >> 6);  // wave id 0..4 = j-decet
    float acc[10];
#pragma unroll
    for (int jj = 0; jj < 10; ++jj) acc[jj] = 0.f;

    for (int r = 0; r < D1_KPB / D1_SUB; ++r) {
        int k0 = blockIdx.x * D1_KPB + r * D1_SUB;
        __syncthreads();
        for (int u = t; u < 64 * D1_SUB; u += 320) {
            int bb = u >> 7;
            int i  = u & (D1_SUB - 1);
            XT[i][bb] = x2[bb * 131072 + k0 + i];
        }
        __syncthreads();
        for (int k = 0; k < D1_SUB; ++k) {
            float xv = XT[k][b];
            const float* wr = dw1 + (k0 + k) * 50 + jg * 10;  // uniform -> s_load
#pragma unroll
            for (int jj = 0; jj < 10; ++jj)
                acc[jj] += xv * wr[jj];
        }
    }
    // partial layout: [block][j][b]
    float* po = partial + blockIdx.x * 3200 + jg * 640 + b;
#pragma unroll
    for (int jj = 0; jj < 10; ++jj) po[jj * 64] = acc[jj];
}

// ---------------- Dense 1 reduce: sum 512 partials ---------------------------
__global__ void d1_reduce(const float* __restrict__ partial, float* __restrict__ h) {
    int t = blockIdx.x * blockDim.x + threadIdx.x;
    if (t >= 3200) return;
    float s0 = 0.f, s1 = 0.f, s2 = 0.f, s3 = 0.f;
    for (int cb = 0; cb < D1_NB; cb += 4) {
        s0 += partial[(cb + 0) * 3200 + t];
        s1 += partial[(cb + 1) * 3200 + t];
        s2 += partial[(cb + 2) * 3200 + t];
        s3 += partial[(cb + 3) * 3200 + t];
    }
    h[t] = (s0 + s1) + (s2 + s3);   // h layout [j][b]
}

// ---------------- Dense 2 + softmax ------------------------------------------
__global__ void d2_kernel(const float* __restrict__ h, const float* __restrict__ db1,
                          const float* __restrict__ dw2, const float* __restrict__ db2,
                          float* __restrict__ out) {
    int b = threadIdx.x;  // 0..63
    float a[10];
#pragma unroll
    for (int j = 0; j < 10; ++j) a[j] = db2[j];
    for (int i = 0; i < 50; ++i) {
        float v = fmaxf(h[i * 64 + b] + db1[i], 0.f);
#pragma unroll
        for (int j = 0; j < 10; ++j) a[j] += v * dw2[i * 10 + j];
    }
    float mx = a[0];
#pragma unroll
    for (int j = 1; j < 10; ++j) mx = fmaxf(mx, a[j]);
    float s = 0.f;
#pragma unroll
    for (int j = 0; j < 10; ++j) { a[j] = expf(a[j] - mx); s += a[j]; }
    float inv = 1.f / s;
#pragma unroll
    for (int j = 0; j < 10; ++j) out[b * 10 + j] = a[j] * inv;
}

// -----------------------------------------------------------------------------
extern "C" void kernel_launch(void* const* d_in, const int* in_sizes, int n_in,
                              void* d_out, int out_size, void* d_ws, size_t ws_size,
                              hipStream_t stream) {
    const float* inputs = (const float*)d_in[0];
    const float* cw0 = (const float*)d_in[1];
    const float* cb0 = (const float*)d_in[2];
    const float* cw1 = (const float*)d_in[3];
    const float* cb1 = (const float*)d_in[4];
    const float* cw2 = (const float*)d_in[5];
    const float* cb2 = (const float*)d_in[6];
    const float* dw1 = (const float*)d_in[7];
    const float* db1 = (const float*)d_in[8];
    const float* dw2 = (const float*)d_in[9];
    const float* db2 = (const float*)d_in[10];
    float* out = (float*)d_out;

    float* ws = (float*)d_ws;
    // x1 @ 0 (8388608 f), x0 @ 8388608 (4194304 f), x2 @ 8388608 (over dead x0),
    // partial @ 0 (512*3200 over dead x1), h @ 1638400 (3200).
    float* x1      = ws;
    float* x0      = ws + 8388608;
    float* x2      = ws + 8388608;
    float* partial = ws;
    float* h       = ws + 1638400;

    l0_kernel<<<1024, 256, 0, stream>>>(inputs, cw0, cb0, x0);
    l1_kernel<<<1024, 256, 0, stream>>>(x0, cw1, cb1, x1);
    l2_kernel<<<1024, 256, 0, stream>>>(x1, cw2, cb2, x2);
    d1_kernel<<<D1_NB, 320, 0, stream>>>(x2, dw1, partial);
    d1_reduce<<<13, 256, 0, stream>>>(partial, h);
    d2_kernel<<<1, 64, 0, stream>>>(h, db1, dw2, db2, out);
}

// Round 3
// 332.085 us; speedup vs baseline: 3.8162x; 1.5496x over previous
//
#include <hip/hip_runtime.h>
#include <hip/hip_bf16.h>
#include <math.h>

typedef unsigned short ushort_t;

// ---------------------------------------------------------------------------
// CNNModel: planar-layout rewrite.
//   x1g[g][b][j][32][34] bf16 (col-halo padded)  @ ws f32-offset 0       (4,456,448)
//   x0t[b][r][ci][32][34] f32                    @ 4,456,448             (4,456,448)
//   x2 flat NHWC f32                             @ 4,456,448 (over dead x0t, 8,388,608)
//   partial @ 0 (over dead x1g), h @ 2,000,000, w1p @ 12,845,056 (+18,432)
// Footprint: 12,863,488 f32 = 51.5 MB (< 67 MB proven safe in R1/R2).
// ---------------------------------------------------------------------------

#define PLANE 1088   // 32*34
#define X0T_OFF 4456448
#define X2_OFF  4456448
#define H_OFF   2000000
#define W1P_OFF 12845056

__device__ __forceinline__ float bf2f(ushort_t u) {
    union { unsigned int i; float f; } c; c.i = ((unsigned int)u) << 16; return c.f;
}
__device__ __forceinline__ ushort_t f2bf(float f) {
    union { float f; unsigned int i; } c; c.f = f;
    unsigned int r = c.i + 0x7fffu + ((c.i >> 16) & 1u);   // RNE
    return (ushort_t)(r >> 16);
}

// ---------------- halo zero: col 0 / col 33 of every plane -------------------
__global__ void halo_zero(float* __restrict__ x0t, ushort_t* __restrict__ x1g) {
    int t = blockIdx.x * blockDim.x + threadIdx.x;
    const int NC0 = 4096 * 64;               // x0t planes
    if (t < NC0) {
        int p = t >> 6, i = t & 63;
        x0t[p * PLANE + (i >> 1) * 34 + (i & 1) * 33] = 0.f;
    } else {
        t -= NC0;                            // 8192*64 x1g cells
        int p = t >> 6, i = t & 63;
        x1g[p * PLANE + (i >> 1) * 34 + (i & 1) * 33] = 0;
    }
}

// ---------------- w1 repack: w1p[i0][tap][f][q] ------------------------------
__global__ void w1_pack(const float* __restrict__ cw1, float* __restrict__ w1p) {
    int t = blockIdx.x * blockDim.x + threadIdx.x;   // 18432
    int q = t & 7, f = (t >> 3) & 15, r_ = t >> 7;
    int tap = r_ % 9, i0 = r_ / 9;
    w1p[t] = cw1[(tap * 16 + f) * 128 + i0 + 16 * q];
}

// ---------------- Layer 0: dense conv 3 -> 64, write planar ------------------
__global__ __launch_bounds__(256) void l0_kernel(const float* __restrict__ in,
    const float* __restrict__ w, const float* __restrict__ bias, float* __restrict__ x0t) {
    int bi = blockIdx.x;
    int cib = bi & 3;             // ci block: channels cib*16 + k (r=k, ci=cib)
    int rb  = (bi >> 2) & 3;
    int b   = bi >> 4;
    int t = threadIdx.x, lane = t & 63, wv = t >> 6;
    int col = lane & 31;
    int row = rb * 8 + wv * 2 + (lane >> 5);
    int n0 = cib * 16;

    float acc[16];
#pragma unroll
    for (int k = 0; k < 16; ++k) acc[k] = bias[n0 + k];

    for (int ky = 0; ky < 3; ++ky) {
        int yy = row + ky - 1;
        for (int kx = 0; kx < 3; ++kx) {
            int xx = col + kx - 1;
            if ((unsigned)yy < 32u && (unsigned)xx < 32u) {
                const float* pb = in + ((b * 32 + yy) * 32 + xx) * 3;
                float p0 = pb[0], p1 = pb[1], p2 = pb[2];
                const float* wb = w + (ky * 3 + kx) * 3 * 64 + n0;
#pragma unroll
                for (int c = 0; c < 3; ++c) {
                    float pc = (c == 0) ? p0 : ((c == 1) ? p1 : p2);
#pragma unroll
                    for (int k = 0; k < 16; ++k) acc[k] += pc * wb[c * 64 + k];
                }
            }
        }
    }
    // store planar: x0t[b][k][cib][row][col+1]
#pragma unroll
    for (int k = 0; k < 16; ++k) {
        x0t[(((b * 16 + k) * 4 + cib) * 32 + row) * 34 + col + 1] = fmaxf(acc[k], 0.f);
    }
}

// ---------------- Layer 1: fan-in 16, groups by i0, write x1g planar ---------
__global__ __launch_bounds__(256) void l1_kernel(const float* __restrict__ x0t,
    const float* __restrict__ w1p, const float* __restrict__ cb1, ushort_t* __restrict__ x1g) {
    int bi = blockIdx.x;
    int i0 = bi & 15;
    int b  = bi >> 4;
    int t = threadIdx.x, lane = t & 63;
    int col = lane & 31;
    int rs = (t >> 6) * 2 + (lane >> 5);   // 0..7

    float acc[4][8];
#pragma unroll
    for (int q = 0; q < 8; ++q) {
        float bq = cb1[i0 + 16 * q];
#pragma unroll
        for (int p = 0; p < 4; ++p) acc[p][q] = bq;
    }

    const float* x0b = x0t + b * 64 * PLANE;
    const float* wb  = w1p + i0 * 9 * 128;

    for (int dy = 0; dy < 3; ++dy) {
        int sp[4]; bool v[4];
#pragma unroll
        for (int p = 0; p < 4; ++p) {
            int row = rs + 8 * p;
            int iy = row + dy - 1;
            v[p] = (unsigned)iy < 32u;
            int iyc = iy < 0 ? 0 : (iy > 31 ? 31 : iy);
            sp[p] = iyc * 34 + col;
        }
        for (int dx = 0; dx < 3; ++dx) {
            const float* wt = wb + (dy * 3 + dx) * 128;
#pragma unroll
            for (int m = 0; m < 4; ++m) {
                int r = (i0 >= 3) ? (i0 - 3 + m) : ((m <= i0) ? m : 12 + m);
#pragma unroll
                for (int ci = 0; ci < 4; ++ci) {
                    const float* wf = wt + (4 * ci + m) * 8;
                    const float* xp = x0b + (r * 4 + ci) * PLANE + dx;
#pragma unroll
                    for (int p = 0; p < 4; ++p) {
                        float px = xp[sp[p]];
                        px = v[p] ? px : 0.f;
#pragma unroll
                        for (int q = 0; q < 8; ++q) acc[p][q] += px * wf[q];
                    }
                }
            }
        }
    }
    // store: n = i0+16q -> g=i0&3, plane=(i0>>2)+4q ; x1g[g][b][plane][row][col+1]
    int g = i0 & 3, jb = i0 >> 2;
    ushort_t* ob = x1g + (g * 64 + b) * 32 * PLANE;
#pragma unroll
    for (int p = 0; p < 4; ++p) {
        int row = rs + 8 * p;
#pragma unroll
        for (int q = 0; q < 8; ++q) {
            ob[(jb + 4 * q) * PLANE + row * 34 + col + 1] = f2bf(fmaxf(acc[p][q], 0.f));
        }
    }
}

// ---------------- Layer 2: fan-in 32, contiguous out quads, read x1g ---------
__global__ __launch_bounds__(256) void l2_kernel(const ushort_t* __restrict__ x1g,
    const float* __restrict__ cw2, const float* __restrict__ cb2, float* __restrict__ x2) {
    int bi = blockIdx.x;
    int n0 = (bi & 3) * 32;
    int rowbase = ((bi >> 2) & 1) * 16;
    int b  = bi >> 3;
    int t = threadIdx.x, lane = t & 63;
    int col = lane & 31;
    int rs = (t >> 6) * 2 + (lane >> 5);   // 0..7

    float4 acc[2][8];
#pragma unroll
    for (int q = 0; q < 8; ++q) {
        float4 bq = *(const float4*)(cb2 + n0 + 4 * q);
        acc[0][q] = bq; acc[1][q] = bq;
    }

    const ushort_t* pg0 = x1g + (0 * 64 + b) * 32 * PLANE;
    const ushort_t* pg1 = x1g + (1 * 64 + b) * 32 * PLANE;
    const ushort_t* pg2 = x1g + (2 * 64 + b) * 32 * PLANE;
    const ushort_t* pg3 = x1g + (3 * 64 + b) * 32 * PLANE;

    for (int dy = 0; dy < 3; ++dy) {
        int row0 = rowbase + rs, row1 = row0 + 8;
        int iy0 = row0 + dy - 1, iy1 = row1 + dy - 1;
        bool v0 = (unsigned)iy0 < 32u, v1 = (unsigned)iy1 < 32u;
        int iyc0 = iy0 < 0 ? 0 : (iy0 > 31 ? 31 : iy0);
        int iyc1 = iy1 < 0 ? 0 : (iy1 > 31 ? 31 : iy1);
        for (int dx = 0; dx < 3; ++dx) {
            int sp0 = iyc0 * 34 + col + dx;
            int sp1 = iyc1 * 34 + col + dx;
            const float* wt = cw2 + (dy * 3 + dx) * 32 * 128 + n0;
#pragma unroll 4
            for (int j = 0; j < 32; ++j) {
                int jo = j * PLANE;
                float a00 = bf2f(pg0[jo + sp0]), a01 = bf2f(pg0[jo + sp1]);
                float a10 = bf2f(pg1[jo + sp0]), a11 = bf2f(pg1[jo + sp1]);
                float a20 = bf2f(pg2[jo + sp0]), a21 = bf2f(pg2[jo + sp1]);
                float a30 = bf2f(pg3[jo + sp0]), a31 = bf2f(pg3[jo + sp1]);
                a00 = v0 ? a00 : 0.f; a10 = v0 ? a10 : 0.f;
                a20 = v0 ? a20 : 0.f; a30 = v0 ? a30 : 0.f;
                a01 = v1 ? a01 : 0.f; a11 = v1 ? a11 : 0.f;
                a21 = v1 ? a21 : 0.f; a31 = v1 ? a31 : 0.f;
                const float* wr = wt + j * 128;
#pragma unroll
                for (int q = 0; q < 8; ++q) {
                    float4 wq = *(const float4*)(wr + 4 * q);
                    acc[0][q].x += a00 * wq.x; acc[0][q].y += a10 * wq.y;
                    acc[0][q].z += a20 * wq.z; acc[0][q].w += a30 * wq.w;
                    acc[1][q].x += a01 * wq.x; acc[1][q].y += a11 * wq.y;
                    acc[1][q].z += a21 * wq.z; acc[1][q].w += a31 * wq.w;
                }
            }
        }
    }
    // store flat NHWC
#pragma unroll
    for (int p = 0; p < 2; ++p) {
        int row = rowbase + rs + 8 * p;
        float* ob = x2 + b * 131072 + (row * 32 + col) * 128 + n0;
#pragma unroll
        for (int q = 0; q < 8; ++q) {
            float4 o;
            o.x = fmaxf(acc[p][q].x, 0.f); o.y = fmaxf(acc[p][q].y, 0.f);
            o.z = fmaxf(acc[p][q].z, 0.f); o.w = fmaxf(acc[p][q].w, 0.f);
            *(float4*)(ob + 4 * q) = o;
        }
    }
}

// ---------------- Dense 1: [64,131072] x [131072,50] -------------------------
#define D1_NB 512
#define D1_KPB 256
#define D1_SUB 128
__global__ __launch_bounds__(320) void d1_kernel(const float* __restrict__ x2,
                                                 const float* __restrict__ dw1,
                                                 float* __restrict__ partial) {
    __shared__ float XT[D1_SUB][65];
    int t = threadIdx.x;
    int b = t & 63;
    int jg = __builtin_amdgcn_readfirstlane(t >> 6);
    float acc[10];
#pragma unroll
    for (int jj = 0; jj < 10; ++jj) acc[jj] = 0.f;

    for (int r = 0; r < D1_KPB / D1_SUB; ++r) {
        int k0 = blockIdx.x * D1_KPB + r * D1_SUB;
        __syncthreads();
        for (int u = t; u < 64 * D1_SUB; u += 320) {
            int bb = u >> 7;
            int i  = u & (D1_SUB - 1);
            XT[i][bb] = x2[bb * 131072 + k0 + i];
        }
        __syncthreads();
        for (int k = 0; k < D1_SUB; ++k) {
            float xv = XT[k][b];
            const float* wr = dw1 + (k0 + k) * 50 + jg * 10;
#pragma unroll
            for (int jj = 0; jj < 10; ++jj)
                acc[jj] += xv * wr[jj];
        }
    }
    float* po = partial + blockIdx.x * 3200 + jg * 640 + b;
#pragma unroll
    for (int jj = 0; jj < 10; ++jj) po[jj * 64] = acc[jj];
}

__global__ void d1_reduce(const float* __restrict__ partial, float* __restrict__ h) {
    int t = blockIdx.x * blockDim.x + threadIdx.x;
    if (t >= 3200) return;
    float s0 = 0.f, s1 = 0.f, s2 = 0.f, s3 = 0.f;
    for (int cb = 0; cb < D1_NB; cb += 4) {
        s0 += partial[(cb + 0) * 3200 + t];
        s1 += partial[(cb + 1) * 3200 + t];
        s2 += partial[(cb + 2) * 3200 + t];
        s3 += partial[(cb + 3) * 3200 + t];
    }
    h[t] = (s0 + s1) + (s2 + s3);
}

__global__ void d2_kernel(const float* __restrict__ h, const float* __restrict__ db1,
                          const float* __restrict__ dw2, const float* __restrict__ db2,
                          float* __restrict__ out) {
    int b = threadIdx.x;
    float a[10];
#pragma unroll
    for (int j = 0; j < 10; ++j) a[j] = db2[j];
    for (int i = 0; i < 50; ++i) {
        float v = fmaxf(h[i * 64 + b] + db1[i], 0.f);
#pragma unroll
        for (int j = 0; j < 10; ++j) a[j] += v * dw2[i * 10 + j];
    }
    float mx = a[0];
#pragma unroll
    for (int j = 1; j < 10; ++j) mx = fmaxf(mx, a[j]);
    float s = 0.f;
#pragma unroll
    for (int j = 0; j < 10; ++j) { a[j] = expf(a[j] - mx); s += a[j]; }
    float inv = 1.f / s;
#pragma unroll
    for (int j = 0; j < 10; ++j) out[b * 10 + j] = a[j] * inv;
}

// -----------------------------------------------------------------------------
extern "C" void kernel_launch(void* const* d_in, const int* in_sizes, int n_in,
                              void* d_out, int out_size, void* d_ws, size_t ws_size,
                              hipStream_t stream) {
    const float* inputs = (const float*)d_in[0];
    const float* cw0 = (const float*)d_in[1];
    const float* cb0 = (const float*)d_in[2];
    const float* cw1 = (const float*)d_in[3];
    const float* cb1 = (const float*)d_in[4];
    const float* cw2 = (const float*)d_in[5];
    const float* cb2 = (const float*)d_in[6];
    const float* dw1 = (const float*)d_in[7];
    const float* db1 = (const float*)d_in[8];
    const float* dw2 = (const float*)d_in[9];
    const float* db2 = (const float*)d_in[10];
    float* out = (float*)d_out;

    float* ws = (float*)d_ws;
    ushort_t* x1g = (ushort_t*)ws;           // bf16 planes, f32-units [0 .. 4,456,448)
    float* x0t    = ws + X0T_OFF;            // [4,456,448 .. 8,912,896)
    float* x2     = ws + X2_OFF;             // over dead x0t, ends 12,845,056
    float* partial = ws;                      // over dead x1g
    float* h      = ws + H_OFF;
    float* w1p    = ws + W1P_OFF;

    halo_zero<<<3072, 256, 0, stream>>>(x0t, x1g);
    w1_pack<<<72, 256, 0, stream>>>(cw1, w1p);
    l0_kernel<<<1024, 256, 0, stream>>>(inputs, cw0, cb0, x0t);
    l1_kernel<<<1024, 256, 0, stream>>>(x0t, w1p, cb1, x1g);
    l2_kernel<<<512, 256, 0, stream>>>(x1g, cw2, cb2, x2);
    d1_kernel<<<D1_NB, 320, 0, stream>>>(x2, dw1, partial);
    d1_reduce<<<13, 256, 0, stream>>>(partial, h);
    d2_kernel<<<1, 64, 0, stream>>>(h, db1, dw2, db2, out);
}